// Round 12
// baseline (159.278 us; speedup 1.0000x reference)
//
#include <hip/hip_runtime.h>
#include <math.h>

// Performer FAVOR+ feature map — single kernel, two-tile software pipeline.
//   out[t][j] = exp2( acc*log2e + dlog[t] ) + ratio*eps
//   dlog[t] = -0.5*||x[t]||^2*log2e - 4   (ratio=2^-4 folded into exponent)
//   bf16 hi/lo 3-term MFMA (drop lo*lo; absmax 3e-8, verified R2..R11).
//
// R12 delta vs R11 (best, 158.1): block owns 256 tokens = two 128-token
// halves sharing one LDS buffer. Half B's x-loads are issued immediately
// after the first barrier so their ~900-cyc HBM latency hides under half A's
// compute+store burst; proj frag build amortized over 2x tokens; half the
// blocks -> fewer in-phase ramps.
//
// Per half: stage (cvt + ds_write_b128, conflict-free) -> barrier ->
// compute: wave w owns feats [32w,32w+32): 8 tt x {4 ds_read_b128 + 12 MFMA
// + 8 exp2 + stores}.

typedef short bf16x8 __attribute__((ext_vector_type(8)));
typedef float f32x4  __attribute__((ext_vector_type(4)));

__device__ __forceinline__ unsigned short f2bf_rne(float f) {
    unsigned u = __builtin_bit_cast(unsigned, f);
    unsigned r = u + 0x7FFFu + ((u >> 16) & 1u);
    return (unsigned short)(r >> 16);
}

__device__ __forceinline__ void f2bf_hilo(float f, unsigned short& h, unsigned short& l) {
    h = f2bf_rne(f);
    float fh = __builtin_bit_cast(float, (unsigned)h << 16);
    l = f2bf_rne(f - fh);
}

__global__ __launch_bounds__(512, 4)
void performer_fm_kernel(const float* __restrict__ x,
                         const float* __restrict__ proj,
                         float* __restrict__ out) {
    // x frags: 8 tt x 4 frags(h0,l0,h1,l1) x 64 lanes x 16 B = 32 KB (reused)
    __shared__ __align__(16) short Af[8 * 4 * 64 * 8];
    __shared__ float dlg[128];

    const int wave = threadIdx.x >> 6;
    const int lane = threadIdx.x & 63;
    const int q    = lane >> 4;
    const int li   = lane & 15;
    const long t0  = (long)blockIdx.x * 256;

    const float NHL2E = -0.7213475204444817f;    // -0.5*log2(e)
    const float LOG2E = 1.4426950408889634f;
    const float REPS  = 6.25e-6f;                // ratio*eps
    bf16x8* Asw = (bf16x8*)Af;
    const bf16x8* As = (const bf16x8*)Af;
    const int sbase = wave * 4 * 64 + lane;      // staging slot (tt = wave)

    // ---- half A x-loads ----
    const float4* xr = (const float4*)(x + (t0 + wave * 16 + li) * 64);
    float4 a0 = xr[q * 2];
    float4 a1 = xr[q * 2 + 1];
    float4 a2 = xr[8 + q * 2];
    float4 a3 = xr[8 + q * 2 + 1];

    // ---- proj fragments in-register (L2-hot; overlaps x latency) ----
    bf16x8 Ph[2][2], Pl[2][2];
    {
        const float nrm = 0.35355339059327373f;  // 64^-0.25
        #pragma unroll
        for (int nf = 0; nf < 2; ++nf) {
            const int n = (wave * 2 + nf) * 16 + li;
            #pragma unroll
            for (int kc = 0; kc < 2; ++kc) {
                const int kb = kc * 32 + q * 8;
                float4 v0 = *(const float4*)&proj[n * 64 + kb];
                float4 v1 = *(const float4*)&proj[n * 64 + kb + 4];
                float vals[8] = {v0.x, v0.y, v0.z, v0.w, v1.x, v1.y, v1.z, v1.w};
                union { unsigned short us[8]; bf16x8 v; } hh, ll;
                #pragma unroll
                for (int j = 0; j < 8; ++j)
                    f2bf_hilo(vals[j] * nrm, hh.us[j], ll.us[j]);
                Ph[nf][kc] = hh.v;
                Pl[nf][kc] = ll.v;
            }
        }
    }

    // ---- stage half A ----
    {
        float p = a0.x * a0.x + a0.y * a0.y + a0.z * a0.z + a0.w * a0.w
                + a1.x * a1.x + a1.y * a1.y + a1.z * a1.z + a1.w * a1.w
                + a2.x * a2.x + a2.y * a2.y + a2.z * a2.z + a2.w * a2.w
                + a3.x * a3.x + a3.y * a3.y + a3.z * a3.z + a3.w * a3.w;
        p += __shfl_xor(p, 16);
        p += __shfl_xor(p, 32);
        if (q == 0) dlg[wave * 16 + li] = fmaf(NHL2E, p, -4.0f);
        float v0[8] = {a0.x, a0.y, a0.z, a0.w, a1.x, a1.y, a1.z, a1.w};
        float v1[8] = {a2.x, a2.y, a2.z, a2.w, a3.x, a3.y, a3.z, a3.w};
        union { unsigned short us[8]; bf16x8 v; } h0, l0, h1, l1;
        #pragma unroll
        for (int j = 0; j < 8; ++j) {
            f2bf_hilo(v0[j], h0.us[j], l0.us[j]);
            f2bf_hilo(v1[j], h1.us[j], l1.us[j]);
        }
        Asw[sbase]       = h0.v;
        Asw[sbase + 64]  = l0.v;
        Asw[sbase + 128] = h1.v;
        Asw[sbase + 192] = l1.v;
    }
    __syncthreads();

    // ---- prefetch half B x (latency hides under compute A) ----
    const float4* xrB = (const float4*)(x + (t0 + 128 + wave * 16 + li) * 64);
    float4 b0 = xrB[q * 2];
    float4 b1 = xrB[q * 2 + 1];
    float4 b2 = xrB[8 + q * 2];
    float4 b3 = xrB[8 + q * 2 + 1];

    // ---- compute + store half A ----
    #pragma unroll 2
    for (int tt = 0; tt < 8; ++tt) {
        const int ab = tt * 256 + lane;
        bf16x8 xh0 = As[ab];
        bf16x8 xl0 = As[ab + 64];
        bf16x8 xh1 = As[ab + 128];
        bf16x8 xl1 = As[ab + 192];
        float4 dl  = *(const float4*)&dlg[tt * 16 + q * 4];

        float* ob = out + (t0 + tt * 16 + q * 4) * 256 + wave * 32 + li;
        #pragma unroll
        for (int nf = 0; nf < 2; ++nf) {
            f32x4 acc = {0.f, 0.f, 0.f, 0.f};
            acc = __builtin_amdgcn_mfma_f32_16x16x32_bf16(xl0, Ph[nf][0], acc, 0, 0, 0);
            acc = __builtin_amdgcn_mfma_f32_16x16x32_bf16(xh0, Pl[nf][0], acc, 0, 0, 0);
            acc = __builtin_amdgcn_mfma_f32_16x16x32_bf16(xh0, Ph[nf][0], acc, 0, 0, 0);
            acc = __builtin_amdgcn_mfma_f32_16x16x32_bf16(xl1, Ph[nf][1], acc, 0, 0, 0);
            acc = __builtin_amdgcn_mfma_f32_16x16x32_bf16(xh1, Pl[nf][1], acc, 0, 0, 0);
            acc = __builtin_amdgcn_mfma_f32_16x16x32_bf16(xh1, Ph[nf][1], acc, 0, 0, 0);
            ob[0 * 256 + nf * 16] = __builtin_amdgcn_exp2f(fmaf(acc[0], LOG2E, dl.x)) + REPS;
            ob[1 * 256 + nf * 16] = __builtin_amdgcn_exp2f(fmaf(acc[1], LOG2E, dl.y)) + REPS;
            ob[2 * 256 + nf * 16] = __builtin_amdgcn_exp2f(fmaf(acc[2], LOG2E, dl.z)) + REPS;
            ob[3 * 256 + nf * 16] = __builtin_amdgcn_exp2f(fmaf(acc[3], LOG2E, dl.w)) + REPS;
        }
    }
    __syncthreads();     // all reads of Af/dlg done before restage

    // ---- stage half B ----
    {
        float p = b0.x * b0.x + b0.y * b0.y + b0.z * b0.z + b0.w * b0.w
                + b1.x * b1.x + b1.y * b1.y + b1.z * b1.z + b1.w * b1.w
                + b2.x * b2.x + b2.y * b2.y + b2.z * b2.z + b2.w * b2.w
                + b3.x * b3.x + b3.y * b3.y + b3.z * b3.z + b3.w * b3.w;
        p += __shfl_xor(p, 16);
        p += __shfl_xor(p, 32);
        if (q == 0) dlg[wave * 16 + li] = fmaf(NHL2E, p, -4.0f);
        float v0[8] = {b0.x, b0.y, b0.z, b0.w, b1.x, b1.y, b1.z, b1.w};
        float v1[8] = {b2.x, b2.y, b2.z, b2.w, b3.x, b3.y, b3.z, b3.w};
        union { unsigned short us[8]; bf16x8 v; } h0, l0, h1, l1;
        #pragma unroll
        for (int j = 0; j < 8; ++j) {
            f2bf_hilo(v0[j], h0.us[j], l0.us[j]);
            f2bf_hilo(v1[j], h1.us[j], l1.us[j]);
        }
        Asw[sbase]       = h0.v;
        Asw[sbase + 64]  = l0.v;
        Asw[sbase + 128] = h1.v;
        Asw[sbase + 192] = l1.v;
    }
    __syncthreads();

    // ---- compute + store half B ----
    #pragma unroll 2
    for (int tt = 0; tt < 8; ++tt) {
        const int ab = tt * 256 + lane;
        bf16x8 xh0 = As[ab];
        bf16x8 xl0 = As[ab + 64];
        bf16x8 xh1 = As[ab + 128];
        bf16x8 xl1 = As[ab + 192];
        float4 dl  = *(const float4*)&dlg[tt * 16 + q * 4];

        float* ob = out + (t0 + 128 + tt * 16 + q * 4) * 256 + wave * 32 + li;
        #pragma unroll
        for (int nf = 0; nf < 2; ++nf) {
            f32x4 acc = {0.f, 0.f, 0.f, 0.f};
            acc = __builtin_amdgcn_mfma_f32_16x16x32_bf16(xl0, Ph[nf][0], acc, 0, 0, 0);
            acc = __builtin_amdgcn_mfma_f32_16x16x32_bf16(xh0, Pl[nf][0], acc, 0, 0, 0);
            acc = __builtin_amdgcn_mfma_f32_16x16x32_bf16(xh0, Ph[nf][0], acc, 0, 0, 0);
            acc = __builtin_amdgcn_mfma_f32_16x16x32_bf16(xl1, Ph[nf][1], acc, 0, 0, 0);
            acc = __builtin_amdgcn_mfma_f32_16x16x32_bf16(xh1, Pl[nf][1], acc, 0, 0, 0);
            acc = __builtin_amdgcn_mfma_f32_16x16x32_bf16(xh1, Ph[nf][1], acc, 0, 0, 0);
            ob[0 * 256 + nf * 16] = __builtin_amdgcn_exp2f(fmaf(acc[0], LOG2E, dl.x)) + REPS;
            ob[1 * 256 + nf * 16] = __builtin_amdgcn_exp2f(fmaf(acc[1], LOG2E, dl.y)) + REPS;
            ob[2 * 256 + nf * 16] = __builtin_amdgcn_exp2f(fmaf(acc[2], LOG2E, dl.z)) + REPS;
            ob[3 * 256 + nf * 16] = __builtin_amdgcn_exp2f(fmaf(acc[3], LOG2E, dl.w)) + REPS;
        }
    }
}

extern "C" void kernel_launch(void* const* d_in, const int* in_sizes, int n_in,
                              void* d_out, int out_size, void* d_ws, size_t ws_size,
                              hipStream_t stream) {
    const float* x    = (const float*)d_in[0];
    const float* proj = (const float*)d_in[1];
    float* out        = (float*)d_out;
    const int ntok    = in_sizes[0] / 64;        // 131072

    performer_fm_kernel<<<ntok / 256, 512, 0, stream>>>(x, proj, out);
}